// Round 1
// baseline (46820.874 us; speedup 1.0000x reference)
//
#include <hip/hip_runtime.h>
#include <math.h>

// dims
#define BD    64
#define SEQ   64
#define EMBD  512
#define UNITS 1024
#define NG    4096
#define VFR   16000

typedef __attribute__((ext_vector_type(8))) short bf16x8;
typedef __attribute__((ext_vector_type(4))) float f32x4;

__device__ __forceinline__ float sigm(float x) { return 1.0f / (1.0f + __expf(-x)); }
__device__ __forceinline__ float tanh_f(float x) {
    float e = __expf(2.0f * x);
    return 1.0f - 2.0f / (e + 1.0f);
}
__device__ __forceinline__ unsigned bf16bits(float v) {
    unsigned u = __float_as_uint(v);
    return (u + 0x7FFFu + ((u >> 16) & 1u)) >> 16;
}
__device__ __forceinline__ float bf2f(short s) {
    return __uint_as_float(((unsigned)(unsigned short)s) << 16);
}
__device__ __forceinline__ void split2(float v, short& h, short& l) {
    unsigned hb = bf16bits(v);
    float hv = __uint_as_float(hb << 16);
    h = (short)hb;
    l = (short)bf16bits(v - hv);
}

// ---------------- grid barrier (all blocks co-resident: 256 blocks, 1/CU) ---
__device__ __forceinline__ void gbar(int* cnt, int* gen, int nb) {
    __threadfence();
    __syncthreads();
    if (threadIdx.x == 0) {
        int g = __hip_atomic_load(gen, __ATOMIC_RELAXED, __HIP_MEMORY_SCOPE_AGENT);
        if (atomicAdd(cnt, 1) == nb - 1) {
            __hip_atomic_store(cnt, 0, __ATOMIC_RELAXED, __HIP_MEMORY_SCOPE_AGENT);
            __hip_atomic_store(gen, g + 1, __ATOMIC_RELEASE, __HIP_MEMORY_SCOPE_AGENT);
        } else {
            while (__hip_atomic_load(gen, __ATOMIC_RELAXED, __HIP_MEMORY_SCOPE_AGENT) == g)
                __builtin_amdgcn_s_sleep(8);
        }
    }
    __syncthreads();
    __threadfence();
}

__global__ __launch_bounds__(64) void zero16(int* p) {
    if (threadIdx.x < 16) p[threadIdx.x] = 0;
}

// ---------------- prep: embedding gather -> bf16 [4096][512] ----------------
__global__ __launch_bounds__(256) void gather_bf16(
    const float* __restrict__ emb, const int* __restrict__ idx,
    short* __restrict__ dst, int K)
{
    int row = blockIdx.x;
    int g = idx[row];
    const float* src = emb + (size_t)g * K;
    for (int k = threadIdx.x * 2; k < K; k += 512) {
        float2 v = *(const float2*)&src[k];
        dst[(size_t)row * K + k]     = (short)bf16bits(v.x);
        dst[(size_t)row * K + k + 1] = (short)bf16bits(v.y);
    }
}

// ---------------- prep: transpose (+optional split) src[K][N] -> d[N][K] ----
template <bool SPLIT>
__global__ __launch_bounds__(256) void transp_split(
    const float* __restrict__ src, int N, int K,
    short* __restrict__ dh, short* __restrict__ dl)
{
    __shared__ float sm[32][33];
    const int tid = threadIdx.x;
    const int nt = blockIdx.x * 32, kt = blockIdx.y * 32;
    {
        int r = tid >> 3, c4 = (tid & 7) * 4;
        float4 v = *(const float4*)&src[(size_t)(kt + r) * N + nt + c4];
        sm[r][c4] = v.x; sm[r][c4 + 1] = v.y; sm[r][c4 + 2] = v.z; sm[r][c4 + 3] = v.w;
    }
    __syncthreads();
    {
        int n = tid >> 3, k4 = (tid & 7) * 4;
        short4 hh, ll;
        short a, b;
        split2(sm[k4 + 0][n], a, b); hh.x = a; ll.x = b;
        split2(sm[k4 + 1][n], a, b); hh.y = a; ll.y = b;
        split2(sm[k4 + 2][n], a, b); hh.z = a; ll.z = b;
        split2(sm[k4 + 3][n], a, b); hh.w = a; ll.w = b;
        *(short4*)&dh[(size_t)(nt + n) * K + kt + k4] = hh;
        if (SPLIT) *(short4*)&dl[(size_t)(nt + n) * K + kt + k4] = ll;
    }
}

// ---------------- prep: f32 transpose src[K][N] -> dst[N][K] ----------------
__global__ __launch_bounds__(256) void transp_f32(
    const float* __restrict__ src, int N, int K, float* __restrict__ dst)
{
    __shared__ float sm[32][33];
    const int tid = threadIdx.x;
    const int nt = blockIdx.x * 32, kt = blockIdx.y * 32;
    {
        int r = tid >> 3, c4 = (tid & 7) * 4;
        float4 v = *(const float4*)&src[(size_t)(kt + r) * N + nt + c4];
        sm[r][c4] = v.x; sm[r][c4 + 1] = v.y; sm[r][c4 + 2] = v.z; sm[r][c4 + 3] = v.w;
    }
    __syncthreads();
    {
        int n = tid >> 3, k4 = (tid & 7) * 4;
        float4 o;
        o.x = sm[k4 + 0][n]; o.y = sm[k4 + 1][n];
        o.z = sm[k4 + 2][n]; o.w = sm[k4 + 3][n];
        *(float4*)&dst[(size_t)(nt + n) * K + kt + k4] = o;
    }
}

// ---------------- split-bf16 MFMA GEMM: C[M,N] = A[M,K] * B[N,K]^T ----------
// 128x128 tile, 4 waves each 64x64 (4x4 of 16x16x32 mfma).
// OMODE: 0 = f32, 1 = f32 + row-permute (t*64+b -> b*64+t), 2 = bf16 out,
//        3 = f32 scatter to EOT layout [b][col][s] (row = s*64+b).
template <int OMODE, bool SA, bool SB>
__global__ __launch_bounds__(256, 2) void gemm_split(
    const short* __restrict__ Ah, const short* __restrict__ Al,
    const short* __restrict__ Bh, const short* __restrict__ Bl,
    const float* __restrict__ bias, void* __restrict__ Cout, int N, int K)
{
    __shared__ short lds[32 * 512];   // 32 subtiles * 64 lanes * 8 shorts = 32KB
    const int tid = threadIdx.x;
    const int lane = tid & 63, w = tid >> 6;
    const int bm = blockIdx.y, bn = blockIdx.x;
    const int wm = w & 1, wn = w >> 1;
    const int r15 = lane & 15, q = lane >> 4;

    f32x4 zero4 = {0.f, 0.f, 0.f, 0.f};
    f32x4 acc[4][4];
#pragma unroll
    for (int i = 0; i < 4; ++i)
#pragma unroll
        for (int j = 0; j < 4; ++j) acc[i][j] = zero4;

    const short* gsrc[8];
    bool use[8];
#pragma unroll
    for (int i = 0; i < 8; ++i) {
        int st = w * 8 + i;
        int mat = st >> 4, hl = (st >> 3) & 1, mt = st & 7;
        const short* base = (mat == 0) ? (hl ? Al : Ah) : (hl ? Bl : Bh);
        use[i] = (mat == 0) ? (SA || hl == 0) : (SB || hl == 0);
        int row = ((mat == 0) ? bm : bn) * 128 + mt * 16 + r15;
        gsrc[i] = base + (size_t)row * K + q * 8;
    }

    for (int k0 = 0; k0 < K; k0 += 32) {
        int4 stg[8];
#pragma unroll
        for (int i = 0; i < 8; ++i)
            if (use[i]) stg[i] = *(const int4*)(gsrc[i] + k0);
        __syncthreads();
#pragma unroll
        for (int i = 0; i < 8; ++i)
            if (use[i]) *(int4*)&lds[(size_t)((w * 8 + i) * 64 + lane) * 8] = stg[i];
        __syncthreads();

        bf16x8 ah[4], al[4], bh[4], bl[4];
#pragma unroll
        for (int i = 0; i < 4; ++i) {
            ah[i] = *(const bf16x8*)&lds[(((wm * 4 + i) * 64) + lane) * 8];
            if (SA) al[i] = *(const bf16x8*)&lds[(((8 + wm * 4 + i) * 64) + lane) * 8];
            bh[i] = *(const bf16x8*)&lds[(((16 + wn * 4 + i) * 64) + lane) * 8];
            if (SB) bl[i] = *(const bf16x8*)&lds[(((24 + wn * 4 + i) * 64) + lane) * 8];
        }
#pragma unroll
        for (int i = 0; i < 4; ++i)
#pragma unroll
            for (int j = 0; j < 4; ++j) {
                acc[i][j] = __builtin_amdgcn_mfma_f32_16x16x32_bf16(ah[i], bh[j], acc[i][j], 0, 0, 0);
                if (SA) acc[i][j] = __builtin_amdgcn_mfma_f32_16x16x32_bf16(al[i], bh[j], acc[i][j], 0, 0, 0);
                if (SB) acc[i][j] = __builtin_amdgcn_mfma_f32_16x16x32_bf16(ah[i], bl[j], acc[i][j], 0, 0, 0);
            }
    }

#pragma unroll
    for (int i = 0; i < 4; ++i) {
        int rowbase = bm * 128 + wm * 64 + i * 16 + q * 4;
#pragma unroll
        for (int j = 0; j < 4; ++j) {
            int col = bn * 128 + wn * 64 + j * 16 + r15;
            float bv = bias ? bias[col] : 0.f;
#pragma unroll
            for (int rI = 0; rI < 4; ++rI) {
                int row = rowbase + rI;
                float v = acc[i][j][rI] + bv;
                if (OMODE == 1) {
                    int orow = ((row & 63) << 6) | (row >> 6);
                    ((float*)Cout)[(size_t)orow * N + col] = v;
                } else if (OMODE == 0) {
                    ((float*)Cout)[(size_t)row * N + col] = v;
                } else if (OMODE == 3) {
                    // EOT[b][col][s], b = row&63, s = row>>6, 64 s-slots innermost
                    ((float*)Cout)[((size_t)(row & 63) * N + col) * 64 + (row >> 6)] = v;
                } else {
                    ((short*)Cout)[(size_t)row * N + col] = (short)bf16bits(v);
                }
            }
        }
    }
}

// ---------------- shared pieces of the persistent recurrent kernels --------
// z-accumulation of h @ U for 16 columns using UT[n][k] (transposed U).
// Per thread: contiguous 256B float4 chunks of UT, issued before the staging
// barrier so global latency hides under the LDS h-transpose.
__device__ __forceinline__ void accum_hUT(
    float& a0, float& a1, const float* __restrict__ h_ws,
    const float* __restrict__ UT, int n, int b0, int tid,
    float (*hsm)[66])
{
    const float4* ut = (const float4*)&UT[(size_t)n * 1024];
    for (int k0 = 0; k0 < 1024; k0 += 64) {
        float4 uvr[16];
#pragma unroll
        for (int i = 0; i < 16; ++i) uvr[i] = ut[(k0 >> 2) + i];
        __syncthreads();
#pragma unroll
        for (int i = 0; i < 2; ++i) {
            int idx4 = tid * 2 + i;                 // 0..1023
            int bb = idx4 >> 4, kq = (idx4 & 15) * 4;
            float4 v = *(const float4*)&h_ws[bb * 1024 + k0 + kq];
            hsm[kq + 0][bb] = v.x;
            hsm[kq + 1][bb] = v.y;
            hsm[kq + 2][bb] = v.z;
            hsm[kq + 3][bb] = v.w;
        }
        __syncthreads();
#pragma unroll
        for (int kk4 = 0; kk4 < 16; ++kk4) {
            float4 uv = uvr[kk4];
            float2 h0v = *(const float2*)&hsm[kk4 * 4 + 0][b0];
            float2 h1v = *(const float2*)&hsm[kk4 * 4 + 1][b0];
            float2 h2v = *(const float2*)&hsm[kk4 * 4 + 2][b0];
            float2 h3v = *(const float2*)&hsm[kk4 * 4 + 3][b0];
            a0 += h0v.x * uv.x + h1v.x * uv.y + h2v.x * uv.z + h3v.x * uv.w;
            a1 += h0v.y * uv.x + h1v.y * uv.y + h2v.y * uv.z + h3v.y * uv.w;
        }
    }
}

__device__ __forceinline__ void lstm_gate_phase(
    int t, int blk, int tid, const float* __restrict__ z_ws,
    float* __restrict__ h_ws, float* __restrict__ c_ws,
    short* __restrict__ oh, short* __restrict__ ol)
{
    int g2 = blk * 512 + tid;
    if (g2 < 65536) {
        int b = g2 >> 10, u = g2 & 1023;
        const float* zr = z_ws + b * NG;
        float zi = zr[u], zf = zr[u + 1024], zg = zr[u + 2048], zo = zr[u + 3072];
        float cp = c_ws[g2];
        float cn = sigm(zf) * cp + sigm(zi) * tanh_f(zg);
        float hn = sigm(zo) * tanh_f(cn);
        c_ws[g2] = cn;
        h_ws[g2] = hn;
        short hh, hl;
        split2(hn, hh, hl);
        size_t o = (size_t)(t * 64 + b) * 1024 + u;
        oh[o] = hh;
        ol[o] = hl;
    }
}

// ---------------- encoder: 64 steps, persistent, 256 blocks x 512 ----------
__global__ __launch_bounds__(512, 2) void encoder_persist(
    const short* __restrict__ xW,      // bf16 [4096 (b*64+t)][4096]
    const float* __restrict__ UT,      // f32 [4096 n][1024 k]
    float* __restrict__ h_ws, float* __restrict__ c_ws, float* __restrict__ z_ws,
    short* __restrict__ eo_h, short* __restrict__ eo_l,
    int* cnt, int* gen)
{
    __shared__ float hsm[64][66];
    const int tid = threadIdx.x;
    const int blk = blockIdx.x;
    {   // zero h, c
        int g = blk * 512 + tid;
        if (g < 65536) h_ws[g] = 0.f;
        else c_ws[g - 65536] = 0.f;
    }
    gbar(cnt, gen, 256);
    const int c16 = tid & 15, bg = tid >> 4;
    const int n = blk * 16 + c16;
    const int b0 = bg * 2;
    for (int t = 0; t < SEQ; ++t) {
        float a0 = bf2f(xW[(size_t)(b0 * 64 + t) * NG + n]);
        float a1 = bf2f(xW[(size_t)((b0 + 1) * 64 + t) * NG + n]);
        accum_hUT(a0, a1, h_ws, UT, n, b0, tid, hsm);
        z_ws[b0 * NG + n] = a0;
        z_ws[(b0 + 1) * NG + n] = a1;
        gbar(cnt, gen, 256);
        lstm_gate_phase(t, blk, tid, z_ws, h_ws, c_ws, eo_h, eo_l);
        gbar(cnt, gen, 256);
    }
}

// ---------------- decoder: 64 steps, persistent, 256 blocks x 512 ----------
__global__ __launch_bounds__(512, 2) void decoder_persist(
    const short* __restrict__ xW,      // bf16 [4096 (b*64+t)][4096]
    const float* __restrict__ UT,      // f32 [4096 n][1024 k]
    const float* __restrict__ Wq, const float* __restrict__ wv,
    const float* __restrict__ kproj,   // f32 [4096 (s*64+b)][1024]
    const float* __restrict__ EOT,     // f32 [64 b][4096 n][64 s]
    const int* __restrict__ valid_len,
    float* __restrict__ h_ws, float* __restrict__ c_ws, float* __restrict__ z_ws,
    float* __restrict__ q_ws, float* __restrict__ sc_ws,
    short* __restrict__ hs_h, short* __restrict__ hs_l,
    int* cnt, int* gen)
{
    __shared__ float hsm[64][66];
    __shared__ float attn_sm[64][68];
    __shared__ float redq[64][8][4];
    const int tid = threadIdx.x;
    const int blk = blockIdx.x;

    for (int t = 0; t < SEQ; ++t) {
        // ---- phase A: q = h @ Wq (block owns 4 q-columns) ----
        {
            const int b = tid & 63;
            const int p8 = tid >> 6;              // 0..7 K-chunks of 128
            const int kbase = p8 * 128;
            const int u0 = blk * 4;
            float ax = 0.f, ay = 0.f, az = 0.f, aw = 0.f;
            const float* hrow = h_ws + b * 1024 + kbase;
            const float* wbase = Wq + (size_t)kbase * 1024 + u0;
#pragma unroll 8
            for (int k = 0; k < 128; k += 4) {
                float4 hv = *(const float4*)&hrow[k];
                float4 w0 = *(const float4*)&wbase[(size_t)(k + 0) * 1024];
                float4 w1 = *(const float4*)&wbase[(size_t)(k + 1) * 1024];
                float4 w2 = *(const float4*)&wbase[(size_t)(k + 2) * 1024];
                float4 w3 = *(const float4*)&wbase[(size_t)(k + 3) * 1024];
                ax += hv.x * w0.x + hv.y * w1.x + hv.z * w2.x + hv.w * w3.x;
                ay += hv.x * w0.y + hv.y * w1.y + hv.z * w2.y + hv.w * w3.y;
                az += hv.x * w0.z + hv.y * w1.z + hv.z * w2.z + hv.w * w3.z;
                aw += hv.x * w0.w + hv.y * w1.w + hv.z * w2.w + hv.w * w3.w;
            }
            redq[b][p8][0] = ax; redq[b][p8][1] = ay;
            redq[b][p8][2] = az; redq[b][p8][3] = aw;
            __syncthreads();
            if (tid < 64) {
                float sx = 0.f, sy = 0.f, sz = 0.f, sw = 0.f;
#pragma unroll
                for (int p = 0; p < 8; ++p) {
                    sx += redq[tid][p][0]; sy += redq[tid][p][1];
                    sz += redq[tid][p][2]; sw += redq[tid][p][3];
                }
                float4 o = {sx, sy, sz, sw};
                *(float4*)&q_ws[tid * 1024 + u0] = o;
            }
        }
        gbar(cnt, gen, 256);
        // ---- phase B: scores(b,s) = sum_u wv[u]*tanh(q[b,u]+kproj[s,b,u]) ----
        {
            const int p = tid >> 5, l32 = tid & 31;
            const int pair = blk * 16 + p;        // = s*64 + b
            const int b = pair & 63, s = pair >> 6;
            const float* kp = kproj + (size_t)pair * 1024;
            const float* qp = q_ws + b * 1024;
            float a = 0.f;
#pragma unroll
            for (int j = 0; j < 8; ++j) {
                int k = j * 128 + l32 * 4;
                float4 kv = *(const float4*)&kp[k];
                float4 qv = *(const float4*)&qp[k];
                float4 w4 = *(const float4*)&wv[k];
                a += w4.x * tanh_f(qv.x + kv.x);
                a += w4.y * tanh_f(qv.y + kv.y);
                a += w4.z * tanh_f(qv.z + kv.z);
                a += w4.w * tanh_f(qv.w + kv.w);
            }
#pragma unroll
            for (int off = 16; off; off >>= 1) a += __shfl_xor(a, off, 64);
            if (l32 == 0) sc_ws[b * 64 + s] = a;
        }
        gbar(cnt, gen, 256);
        // ---- phase C: z = xW + sum_s attn*EOT + h @ U ----
        {
            if (tid < 64) {                       // per-b softmax (redundant per block)
                const int b = tid;
                const int vl = valid_len[b];
                float mx = -1e30f;
                for (int s = 0; s < 64; ++s) {
                    float v = (s < vl) ? sc_ws[b * 64 + s] : -1000000.0f;
                    attn_sm[b][s] = v;
                    mx = fmaxf(mx, v);
                }
                float sum = 0.f;
                for (int s = 0; s < 64; ++s) {
                    float e = __expf(attn_sm[b][s] - mx);
                    attn_sm[b][s] = e;
                    sum += e;
                }
                float r = 1.f / sum;
                for (int s = 0; s < 64; ++s) attn_sm[b][s] *= r;
            }
            __syncthreads();
            const int c16 = tid & 15, bg = tid >> 4;
            const int n = blk * 16 + c16;
            const int b0 = bg * 2;
            float a0 = bf2f(xW[(size_t)(b0 * 64 + t) * NG + n]);
            float a1 = bf2f(xW[(size_t)((b0 + 1) * 64 + t) * NG + n]);
            // attention context: contiguous 256B rows of EOT per batch row
            const float4* e0 = (const float4*)&EOT[((size_t)b0 * 4096 + n) * 64];
            const float4* e1 = e0 + 65536;        // next batch row: 4096*64/4
            const float4* w0p = (const float4*)&attn_sm[b0][0];
            const float4* w1p = (const float4*)&attn_sm[b0 + 1][0];
#pragma unroll
            for (int s4 = 0; s4 < 16; ++s4) {
                float4 v0 = e0[s4], v1 = e1[s4];
                float4 x0 = w0p[s4], x1 = w1p[s4];
                a0 += v0.x * x0.x + v0.y * x0.y + v0.z * x0.z + v0.w * x0.w;
                a1 += v1.x * x1.x + v1.y * x1.y + v1.z * x1.z + v1.w * x1.w;
            }
            accum_hUT(a0, a1, h_ws, UT, n, b0, tid, hsm);
            z_ws[b0 * NG + n] = a0;
            z_ws[(b0 + 1) * NG + n] = a1;
        }
        gbar(cnt, gen, 256);
        // ---- phase G: gates ----
        lstm_gate_phase(t, blk, tid, z_ws, h_ws, c_ws, hs_h, hs_l);
        gbar(cnt, gen, 256);
    }
}

// ---------------------------------------------------------------------------
extern "C" void kernel_launch(void* const* d_in, const int* in_sizes, int n_in,
                              void* d_out, int out_size, void* d_ws, size_t ws_size,
                              hipStream_t stream)
{
    const int*   en        = (const int*)d_in[0];
    const int*   fr        = (const int*)d_in[1];
    const int*   valid_len = (const int*)d_in[2];
    const float* en_emb    = (const float*)d_in[3];
    const float* de_emb    = (const float*)d_in[4];
    const float* en_W      = (const float*)d_in[5];
    const float* en_U      = (const float*)d_in[6];
    const float* en_b      = (const float*)d_in[7];
    const float* de_W      = (const float*)d_in[8];
    const float* de_U      = (const float*)d_in[9];
    const float* de_b      = (const float*)d_in[10];
    const float* Wq        = (const float*)d_in[11];
    const float* Wk        = (const float*)d_in[12];
    const float* wv        = (const float*)d_in[13];
    const float* Wd        = (const float*)d_in[14];
    const float* bd        = (const float*)d_in[15];
    float* out = (float*)d_out;
    char*  ws  = (char*)d_ws;

    // ---- workspace regions (byte offsets; lifetimes annotated) ----
    float* ENUT  = (float*)(ws + 0);            // f32 [4096][1024] (.. encoder)
    float* EOT   = (float*)(ws + 0);            // f32 [64][4096][64] (EOT gemm .. decoder)
    short* WDT_H = (short*)(ws + 0);            // [16000][1024] (after decoder)
    short* WDT_L = (short*)(ws + 33554432);
    short* XWEN  = (short*)(ws + 67108864);     // bf16 [4096][4096] (.. encoder)
    float* KPROJ = (float*)(ws + 67108864);     // f32 [4096][1024] (after encoder)
    float* DEUT  = (float*)(ws + 83886080);     // f32 [4096][1024] (after encoder)
    short* XWFR  = (short*)(ws + 100663296);    // bf16 [4096][4096] (.. decoder)
    short* XEN   = (short*)(ws + 134217728);    // bf16 [4096][512]
    short* XFR   = (short*)(ws + 138412032);
    short* WCT_H = (short*)(ws + 134217728);    // bf16 [4096][1024] (after xW gemms)
    short* WCT_L = (short*)(ws + 142606336);
    short* HS_H  = (short*)(ws + 134217728);    // bf16 [4096][1024] (decoder ..)
    short* HS_L  = (short*)(ws + 142606336);
    short* ENWT  = (short*)(ws + 150994944);    // bf16 [4096][512]
    short* WXT   = (short*)(ws + 155189248);
    short* EO_H  = (short*)(ws + 150994944);    // bf16 [4096][1024] (encoder ..)
    short* EO_L  = (short*)(ws + 159383552);
    short* WKT_H = (short*)(ws + 167772160);    // bf16 [1024][1024]
    short* WKT_L = (short*)(ws + 169869312);
    float* ZWS   = (float*)(ws + 171966464);    // [64][4096]
    float* HWS   = (float*)(ws + 173015040);    // [64][1024]
    float* CWS   = (float*)(ws + 173277184);
    float* QWS   = (float*)(ws + 173539328);
    float* SCWS  = (float*)(ws + 173801472);    // [64][64]
    int*   BAR   = (int*)(ws + 173817856);      // cnt, gen

    zero16<<<1, 64, 0, stream>>>(BAR);

    // embedding gathers (single bf16: xW values are tiny, error negligible)
    gather_bf16<<<4096, 256, 0, stream>>>(en_emb, en, XEN, EMBD);
    gather_bf16<<<4096, 256, 0, stream>>>(de_emb, fr, XFR, EMBD);
    // weight transposes
    transp_split<false><<<dim3(128, 16), 256, 0, stream>>>(en_W, NG, EMBD, ENWT, nullptr);
    transp_split<false><<<dim3(128, 16), 256, 0, stream>>>(de_W + (size_t)UNITS * NG, NG, EMBD, WXT, nullptr);
    // en_U^T f32 (into EOT region, free until EOT gemm)
    transp_f32<<<dim3(128, 32), 256, 0, stream>>>(en_U, NG, UNITS, ENUT);

    // xW = X @ W + b   (bf16 out)
    gemm_split<2, false, false><<<dim3(32, 32), 256, 0, stream>>>(
        XEN, XEN, ENWT, ENWT, en_b, XWEN, NG, EMBD);
    gemm_split<2, false, false><<<dim3(32, 32), 256, 0, stream>>>(
        XFR, XFR, WXT, WXT, de_b, XWFR, NG, EMBD);

    // Wc^T split (into X region, X dead)
    transp_split<true><<<dim3(128, 32), 256, 0, stream>>>(de_W, NG, UNITS, WCT_H, WCT_L);

    // encoder (writes eo splits into ENWT region, dead)
    encoder_persist<<<256, 512, 0, stream>>>(XWEN, ENUT, HWS, CWS, ZWS, EO_H, EO_L, BAR, BAR + 8);

    // de_U^T f32 (into XWEN upper half, dead after encoder)
    transp_f32<<<dim3(128, 32), 256, 0, stream>>>(de_U, NG, UNITS, DEUT);

    // EOT[b][n][s] = (en_o @ Wc) scattered   (f32, overwrites ENUT region)
    gemm_split<3, true, true><<<dim3(32, 32), 256, 0, stream>>>(
        EO_H, EO_L, WCT_H, WCT_L, nullptr, EOT, NG, UNITS);

    // Wk^T split, then kproj = en_o @ Wk (into xW_en region, dead after encoder)
    transp_split<true><<<dim3(32, 32), 256, 0, stream>>>(Wk, UNITS, UNITS, WKT_H, WKT_L);
    gemm_split<0, true, true><<<dim3(8, 32), 256, 0, stream>>>(
        EO_H, EO_L, WKT_H, WKT_L, nullptr, KPROJ, UNITS, UNITS);

    // decoder (writes hs splits into WCT region, dead)
    decoder_persist<<<256, 512, 0, stream>>>(
        XWFR, DEUT, Wq, wv, KPROJ, EOT, valid_len,
        HWS, CWS, ZWS, QWS, SCWS, HS_H, HS_L, BAR, BAR + 8);

    // Wd^T split (into EOT region, dead), then logits with [t][b]->[b][t] permute
    transp_split<true><<<dim3(500, 32), 256, 0, stream>>>(Wd, VFR, UNITS, WDT_H, WDT_L);
    gemm_split<1, true, true><<<dim3(125, 32), 256, 0, stream>>>(
        HS_H, HS_L, WDT_H, WDT_L, bd, out, VFR, UNITS);
}

// Round 2
// 45002.283 us; speedup vs baseline: 1.0404x; 1.0404x over previous
//
#include <hip/hip_runtime.h>
#include <math.h>

// dims
#define BD    64
#define SEQ   64
#define EMBD  512
#define UNITS 1024
#define NG    4096
#define VFR   16000

typedef __attribute__((ext_vector_type(8))) short bf16x8;
typedef __attribute__((ext_vector_type(4))) float f32x4;

__device__ __forceinline__ float sigm(float x) { return 1.0f / (1.0f + __expf(-x)); }
__device__ __forceinline__ float tanh_f(float x) {
    float e = __expf(2.0f * x);
    return 1.0f - 2.0f / (e + 1.0f);
}
__device__ __forceinline__ unsigned bf16bits(float v) {
    unsigned u = __float_as_uint(v);
    return (u + 0x7FFFu + ((u >> 16) & 1u)) >> 16;
}
__device__ __forceinline__ float bf2f(short s) {
    return __uint_as_float(((unsigned)(unsigned short)s) << 16);
}
__device__ __forceinline__ void split2(float v, short& h, short& l) {
    unsigned hb = bf16bits(v);
    float hv = __uint_as_float(hb << 16);
    h = (short)hb;
    l = (short)bf16bits(v - hv);
}

// ---------------- grid barrier (all blocks co-resident: 256 blocks, 1/CU) ---
__device__ __forceinline__ void gbar(int* cnt, int* gen, int nb) {
    __threadfence();
    __syncthreads();
    if (threadIdx.x == 0) {
        int g = __hip_atomic_load(gen, __ATOMIC_RELAXED, __HIP_MEMORY_SCOPE_AGENT);
        if (atomicAdd(cnt, 1) == nb - 1) {
            __hip_atomic_store(cnt, 0, __ATOMIC_RELAXED, __HIP_MEMORY_SCOPE_AGENT);
            __hip_atomic_store(gen, g + 1, __ATOMIC_RELEASE, __HIP_MEMORY_SCOPE_AGENT);
        } else {
            while (__hip_atomic_load(gen, __ATOMIC_RELAXED, __HIP_MEMORY_SCOPE_AGENT) == g)
                __builtin_amdgcn_s_sleep(8);
        }
    }
    __syncthreads();
    __threadfence();
}

__global__ __launch_bounds__(64) void zero16(int* p) {
    if (threadIdx.x < 16) p[threadIdx.x] = 0;
}

// ---------------- prep: embedding gather -> bf16 [4096][512] ----------------
__global__ __launch_bounds__(256) void gather_bf16(
    const float* __restrict__ emb, const int* __restrict__ idx,
    short* __restrict__ dst, int K)
{
    int row = blockIdx.x;
    int g = idx[row];
    const float* src = emb + (size_t)g * K;
    for (int k = threadIdx.x * 2; k < K; k += 512) {
        float2 v = *(const float2*)&src[k];
        dst[(size_t)row * K + k]     = (short)bf16bits(v.x);
        dst[(size_t)row * K + k + 1] = (short)bf16bits(v.y);
    }
}

// ---------------- prep: transpose (+optional split) src[K][N] -> d[N][K] ----
template <bool SPLIT>
__global__ __launch_bounds__(256) void transp_split(
    const float* __restrict__ src, int N, int K,
    short* __restrict__ dh, short* __restrict__ dl)
{
    __shared__ float sm[32][33];
    const int tid = threadIdx.x;
    const int nt = blockIdx.x * 32, kt = blockIdx.y * 32;
    {
        int r = tid >> 3, c4 = (tid & 7) * 4;
        float4 v = *(const float4*)&src[(size_t)(kt + r) * N + nt + c4];
        sm[r][c4] = v.x; sm[r][c4 + 1] = v.y; sm[r][c4 + 2] = v.z; sm[r][c4 + 3] = v.w;
    }
    __syncthreads();
    {
        int n = tid >> 3, k4 = (tid & 7) * 4;
        short4 hh, ll;
        short a, b;
        split2(sm[k4 + 0][n], a, b); hh.x = a; ll.x = b;
        split2(sm[k4 + 1][n], a, b); hh.y = a; ll.y = b;
        split2(sm[k4 + 2][n], a, b); hh.z = a; ll.z = b;
        split2(sm[k4 + 3][n], a, b); hh.w = a; ll.w = b;
        *(short4*)&dh[(size_t)(nt + n) * K + kt + k4] = hh;
        if (SPLIT) *(short4*)&dl[(size_t)(nt + n) * K + kt + k4] = ll;
    }
}

// ---------------- prep: f32 transpose src[K][N] -> dst[N][K] ----------------
__global__ __launch_bounds__(256) void transp_f32(
    const float* __restrict__ src, int N, int K, float* __restrict__ dst)
{
    __shared__ float sm[32][33];
    const int tid = threadIdx.x;
    const int nt = blockIdx.x * 32, kt = blockIdx.y * 32;
    {
        int r = tid >> 3, c4 = (tid & 7) * 4;
        float4 v = *(const float4*)&src[(size_t)(kt + r) * N + nt + c4];
        sm[r][c4] = v.x; sm[r][c4 + 1] = v.y; sm[r][c4 + 2] = v.z; sm[r][c4 + 3] = v.w;
    }
    __syncthreads();
    {
        int n = tid >> 3, k4 = (tid & 7) * 4;
        float4 o;
        o.x = sm[k4 + 0][n]; o.y = sm[k4 + 1][n];
        o.z = sm[k4 + 2][n]; o.w = sm[k4 + 3][n];
        *(float4*)&dst[(size_t)(nt + n) * K + kt + k4] = o;
    }
}

// ---------------- split-bf16 MFMA GEMM: C[M,N] = A[M,K] * B[N,K]^T ----------
// OMODE: 0 = f32, 1 = f32 + row-permute, 2 = bf16 out, 3 = EOT scatter.
template <int OMODE, bool SA, bool SB>
__global__ __launch_bounds__(256, 2) void gemm_split(
    const short* __restrict__ Ah, const short* __restrict__ Al,
    const short* __restrict__ Bh, const short* __restrict__ Bl,
    const float* __restrict__ bias, void* __restrict__ Cout, int N, int K)
{
    __shared__ short lds[32 * 512];
    const int tid = threadIdx.x;
    const int lane = tid & 63, w = tid >> 6;
    const int bm = blockIdx.y, bn = blockIdx.x;
    const int wm = w & 1, wn = w >> 1;
    const int r15 = lane & 15, q = lane >> 4;

    f32x4 zero4 = {0.f, 0.f, 0.f, 0.f};
    f32x4 acc[4][4];
#pragma unroll
    for (int i = 0; i < 4; ++i)
#pragma unroll
        for (int j = 0; j < 4; ++j) acc[i][j] = zero4;

    const short* gsrc[8];
    bool use[8];
#pragma unroll
    for (int i = 0; i < 8; ++i) {
        int st = w * 8 + i;
        int mat = st >> 4, hl = (st >> 3) & 1, mt = st & 7;
        const short* base = (mat == 0) ? (hl ? Al : Ah) : (hl ? Bl : Bh);
        use[i] = (mat == 0) ? (SA || hl == 0) : (SB || hl == 0);
        int row = ((mat == 0) ? bm : bn) * 128 + mt * 16 + r15;
        gsrc[i] = base + (size_t)row * K + q * 8;
    }

    for (int k0 = 0; k0 < K; k0 += 32) {
        int4 stg[8];
#pragma unroll
        for (int i = 0; i < 8; ++i)
            if (use[i]) stg[i] = *(const int4*)(gsrc[i] + k0);
        __syncthreads();
#pragma unroll
        for (int i = 0; i < 8; ++i)
            if (use[i]) *(int4*)&lds[(size_t)((w * 8 + i) * 64 + lane) * 8] = stg[i];
        __syncthreads();

        bf16x8 ah[4], al[4], bh[4], bl[4];
#pragma unroll
        for (int i = 0; i < 4; ++i) {
            ah[i] = *(const bf16x8*)&lds[(((wm * 4 + i) * 64) + lane) * 8];
            if (SA) al[i] = *(const bf16x8*)&lds[(((8 + wm * 4 + i) * 64) + lane) * 8];
            bh[i] = *(const bf16x8*)&lds[(((16 + wn * 4 + i) * 64) + lane) * 8];
            if (SB) bl[i] = *(const bf16x8*)&lds[(((24 + wn * 4 + i) * 64) + lane) * 8];
        }
#pragma unroll
        for (int i = 0; i < 4; ++i)
#pragma unroll
            for (int j = 0; j < 4; ++j) {
                acc[i][j] = __builtin_amdgcn_mfma_f32_16x16x32_bf16(ah[i], bh[j], acc[i][j], 0, 0, 0);
                if (SA) acc[i][j] = __builtin_amdgcn_mfma_f32_16x16x32_bf16(al[i], bh[j], acc[i][j], 0, 0, 0);
                if (SB) acc[i][j] = __builtin_amdgcn_mfma_f32_16x16x32_bf16(ah[i], bl[j], acc[i][j], 0, 0, 0);
            }
    }

#pragma unroll
    for (int i = 0; i < 4; ++i) {
        int rowbase = bm * 128 + wm * 64 + i * 16 + q * 4;
#pragma unroll
        for (int j = 0; j < 4; ++j) {
            int col = bn * 128 + wn * 64 + j * 16 + r15;
            float bv = bias ? bias[col] : 0.f;
#pragma unroll
            for (int rI = 0; rI < 4; ++rI) {
                int row = rowbase + rI;
                float v = acc[i][j][rI] + bv;
                if (OMODE == 1) {
                    int orow = ((row & 63) << 6) | (row >> 6);
                    ((float*)Cout)[(size_t)orow * N + col] = v;
                } else if (OMODE == 0) {
                    ((float*)Cout)[(size_t)row * N + col] = v;
                } else if (OMODE == 3) {
                    ((float*)Cout)[((size_t)(row & 63) * N + col) * 64 + (row >> 6)] = v;
                } else {
                    ((short*)Cout)[(size_t)row * N + col] = (short)bf16bits(v);
                }
            }
        }
    }
}

// ============ persistent recurrent kernels, 256 blocks x 1024 threads =======
// Block owns units u in [blk*4, blk*4+4): its 16 z-columns are
//   n = blk*4 + (nl&3) + 1024*(nl>>2)   for nl = 0..15  (all 4 gates local).
// UT slice (16 rows) lives in LDS transposed [k][16] for the whole kernel
// (LDS survives the L2-invalidating grid barriers). h is staged per step in
// 4 chunks of [64 b][256 k] with conflict-floor b128 patterns. c lives in a
// register of the gate thread. h ping-pongs between two global buffers to
// avoid cross-block WAR on the merged gate phase.

// LDS layout offsets (bytes)
#define UCHT_OFF 0        // float [1024][16]                    = 65536
#define UNI_OFF  65536    // union: hch f32[64][260] (66560)
                          //        red f32[1024][17] (69632)
                          //        redq f32[64][17][4] (17408)  = 69632
#define ATTN_OFF (65536 + 69632)            // f32 [64][68]      = 17408
#define ZSM_OFF  (65536 + 69632 + 17408)    // f32 [16][65]      = 4160
#define ENC_SM   (65536 + 69632 + 4160)
#define DEC_SM   (65536 + 69632 + 17408 + 4160)

__device__ __forceinline__ void stage_ut(const float* __restrict__ UT,
                                         float* __restrict__ uchT,
                                         int n, int nl, int tid)
{
    const float* src = UT + (size_t)n * 1024;   // n is wave-uniform (nl = tid>>6)
    for (int j = 0; j < 16; ++j) {
        int k = (tid & 63) + j * 64;
        uchT[k * 16 + nl] = src[k];
    }
}

__device__ __forceinline__ void stage_h(const float* __restrict__ hr,
                                        float* __restrict__ hch, int c, int tid)
{
    const int b = tid >> 4, k0 = (tid & 15) * 16;
    const float4* s = (const float4*)&hr[b * 1024 + c * 256 + k0];
    float4 v0 = s[0], v1 = s[1], v2 = s[2], v3 = s[3];
    float* d = &hch[b * 260 + k0];
    *(float4*)&d[0]  = v0; *(float4*)&d[4]  = v1;
    *(float4*)&d[8]  = v2; *(float4*)&d[12] = v3;
}

// 4n x 4b register tile over 16 k of chunk c (wave w owns k-sub w*16).
__device__ __forceinline__ void hU_chunk(const float* __restrict__ uchT,
                                         const float* __restrict__ hch,
                                         int c, int nq, int bq, int w, float* acc)
{
#pragma unroll
    for (int kk4 = 0; kk4 < 4; ++kk4) {
        const int kl = w * 16 + kk4 * 4;
        const int kg = c * 256 + kl;
        float4 hv0 = *(const float4*)&hch[(0 * 16 + bq) * 260 + kl];
        float4 hv1 = *(const float4*)&hch[(1 * 16 + bq) * 260 + kl];
        float4 hv2 = *(const float4*)&hch[(2 * 16 + bq) * 260 + kl];
        float4 hv3 = *(const float4*)&hch[(3 * 16 + bq) * 260 + kl];
#pragma unroll
        for (int dk = 0; dk < 4; ++dk) {
            float4 uv = *(const float4*)&uchT[(kg + dk) * 16 + nq * 4];
            float h0 = ((const float*)&hv0)[dk];
            float h1 = ((const float*)&hv1)[dk];
            float h2 = ((const float*)&hv2)[dk];
            float h3 = ((const float*)&hv3)[dk];
            acc[0]  += uv.x * h0; acc[1]  += uv.x * h1; acc[2]  += uv.x * h2; acc[3]  += uv.x * h3;
            acc[4]  += uv.y * h0; acc[5]  += uv.y * h1; acc[6]  += uv.y * h2; acc[7]  += uv.y * h3;
            acc[8]  += uv.z * h0; acc[9]  += uv.z * h1; acc[10] += uv.z * h2; acc[11] += uv.z * h3;
            acc[12] += uv.w * h0; acc[13] += uv.w * h1; acc[14] += uv.w * h2; acc[15] += uv.w * h3;
        }
    }
}

__device__ __forceinline__ void gates_phase(int t, int blk, int tid,
    const float* __restrict__ zsm, float& creg, float* __restrict__ hw,
    short* __restrict__ oh, short* __restrict__ ol)
{
    const int ul = tid >> 6, b = tid & 63, u = blk * 4 + ul;
    float zi = zsm[(0 + ul) * 65 + b];
    float zf = zsm[(4 + ul) * 65 + b];
    float zg = zsm[(8 + ul) * 65 + b];
    float zo = zsm[(12 + ul) * 65 + b];
    float cn = sigm(zf) * creg + sigm(zi) * tanh_f(zg);
    float hn = sigm(zo) * tanh_f(cn);
    creg = cn;
    hw[b * 1024 + u] = hn;
    short hh, hl;
    split2(hn, hh, hl);
    size_t o = (size_t)(t * 64 + b) * 1024 + u;
    oh[o] = hh;
    ol[o] = hl;
}

// ---------------- encoder: 64 steps, 1 gbar/step ----------------------------
__global__ __launch_bounds__(1024, 4) void encoder_persist(
    const short* __restrict__ xW,      // bf16 [4096 (b*64+t)][4096]
    const float* __restrict__ UT,      // f32 [4096 n][1024 k]
    float* __restrict__ h0, float* __restrict__ h1, float* __restrict__ c_ws,
    short* __restrict__ eo_h, short* __restrict__ eo_l,
    int* cnt, int* gen)
{
    __shared__ __align__(16) char SM[ENC_SM];
    float* uchT = (float*)(SM + UCHT_OFF);
    float* UNI  = (float*)(SM + UNI_OFF);
    float* zsm  = (float*)(SM + UNI_OFF + 69632);   // after union
    const int tid = threadIdx.x, blk = blockIdx.x;
    const int nl = tid >> 6, b63 = tid & 63;
    const int n = blk * 4 + (nl & 3) + 1024 * (nl >> 2);
    const int nq = tid & 3, bq = (tid >> 2) & 15, w = tid >> 6;

    stage_ut(UT, uchT, n, nl, tid);
    { int g = blk * 1024 + tid; if (g < 65536) h0[g] = 0.f; }
    float creg = 0.f;
    __syncthreads();
    gbar(cnt, gen, 256);

    for (int t = 0; t < SEQ; ++t) {
        const float* hr = (t & 1) ? h1 : h0;
        float* hw = (t & 1) ? h0 : h1;
        float* hch = UNI;
        float* red = UNI;
        float xwv = bf2f(xW[(size_t)(b63 * 64 + t) * NG + n]);
        float acc[16];
#pragma unroll
        for (int i = 0; i < 16; ++i) acc[i] = 0.f;

        stage_h(hr, hch, 0, tid);
        __syncthreads();
        for (int c = 0; c < 4; ++c) {
            hU_chunk(uchT, hch, c, nq, bq, w, acc);
            __syncthreads();
            if (c < 3) { stage_h(hr, hch, c + 1, tid); __syncthreads(); }
        }
#pragma unroll
        for (int jn = 0; jn < 4; ++jn)
#pragma unroll
            for (int jb = 0; jb < 4; ++jb)
                red[((nq * 4 + jn) * 64 + jb * 16 + bq) * 17 + w] = acc[jn * 4 + jb];
        __syncthreads();
        float s = 0.f;
#pragma unroll
        for (int j = 0; j < 16; ++j) s += red[tid * 17 + j];
        zsm[nl * 65 + b63] = s + xwv;
        __syncthreads();
        if (tid < 256) {
            gates_phase(t, blk, tid, zsm, creg, hw, eo_h, eo_l);
            if (t == SEQ - 1) c_ws[(tid & 63) * 1024 + blk * 4 + (tid >> 6)] = creg;
        }
        gbar(cnt, gen, 256);
    }
}

// ---------------- decoder: 64 steps, 3 gbars/step ---------------------------
__global__ __launch_bounds__(1024, 4) void decoder_persist(
    const short* __restrict__ xW,      // bf16 [4096 (b*64+t)][4096]
    const float* __restrict__ UT,      // f32 [4096 n][1024 k]
    const float* __restrict__ Wq, const float* __restrict__ wv,
    const float* __restrict__ kproj,   // f32 [4096 (s*64+b)][1024]
    const float* __restrict__ EOT,     // f32 [64 b][4096 n][64 s]
    const int* __restrict__ valid_len,
    float* __restrict__ h0, float* __restrict__ h1, const float* __restrict__ c_ws,
    float* __restrict__ q_ws, float* __restrict__ sc_ws,
    short* __restrict__ hs_h, short* __restrict__ hs_l,
    int* cnt, int* gen)
{
    __shared__ __align__(16) char SM[DEC_SM];
    float* uchT = (float*)(SM + UCHT_OFF);
    float* UNI  = (float*)(SM + UNI_OFF);
    float* attn = (float*)(SM + ATTN_OFF);   // [64][68]
    float* zsm  = (float*)(SM + ZSM_OFF);    // [16][65]
    const int tid = threadIdx.x, blk = blockIdx.x;
    const int nl = tid >> 6, b63 = tid & 63;
    const int n = blk * 4 + (nl & 3) + 1024 * (nl >> 2);
    const int nq = tid & 3, bq = (tid >> 2) & 15, w = tid >> 6;

    stage_ut(UT, uchT, n, nl, tid);
    float creg = (tid < 256) ? c_ws[(tid & 63) * 1024 + blk * 4 + (tid >> 6)] : 0.f;
    __syncthreads();

    for (int t = 0; t < SEQ; ++t) {
        const float* hr = (t & 1) ? h1 : h0;
        float* hw = (t & 1) ? h0 : h1;

        // ---- phase A: q = h @ Wq (block owns 4 q-columns) ----
        {
            float* redq = UNI;                 // [64][17][4]
            const int p = tid >> 6;            // 0..15 K-chunks of 64
            const int kbase = p * 64;
            const int u0 = blk * 4;
            float ax = 0.f, ay = 0.f, az = 0.f, aw = 0.f;
            const float* hrow = hr + b63 * 1024 + kbase;
            const float* wb = Wq + (size_t)kbase * 1024 + u0;
#pragma unroll 4
            for (int k = 0; k < 64; k += 4) {
                float4 hv = *(const float4*)&hrow[k];
                float4 w0 = *(const float4*)&wb[(size_t)(k + 0) * 1024];
                float4 w1 = *(const float4*)&wb[(size_t)(k + 1) * 1024];
                float4 w2 = *(const float4*)&wb[(size_t)(k + 2) * 1024];
                float4 w3 = *(const float4*)&wb[(size_t)(k + 3) * 1024];
                ax += hv.x * w0.x + hv.y * w1.x + hv.z * w2.x + hv.w * w3.x;
                ay += hv.x * w0.y + hv.y * w1.y + hv.z * w2.y + hv.w * w3.y;
                az += hv.x * w0.z + hv.y * w1.z + hv.z * w2.z + hv.w * w3.z;
                aw += hv.x * w0.w + hv.y * w1.w + hv.z * w2.w + hv.w * w3.w;
            }
            float4 o = {ax, ay, az, aw};
            *(float4*)&redq[(b63 * 17 + p) * 4] = o;
            __syncthreads();
            if (tid < 64) {
                float sx = 0.f, sy = 0.f, sz = 0.f, sw = 0.f;
#pragma unroll
                for (int p2 = 0; p2 < 16; ++p2) {
                    float4 v = *(const float4*)&redq[(tid * 17 + p2) * 4];
                    sx += v.x; sy += v.y; sz += v.z; sw += v.w;
                }
                float4 qo = {sx, sy, sz, sw};
                *(float4*)&q_ws[tid * 1024 + u0] = qo;
            }
        }
        gbar(cnt, gen, 256);

        // ---- phase B: scores(b,s) = sum_u wv[u]*tanh(q[b,u]+kproj[s,b,u]) --
        {
            const int p = tid >> 6, l = tid & 63;
            const int pair = blk * 16 + p;     // = s*64 + b
            const int bb = pair & 63, ss = pair >> 6;
            const float* kp = kproj + (size_t)pair * 1024;
            const float* qp = q_ws + bb * 1024;
            float a = 0.f;
#pragma unroll
            for (int j = 0; j < 4; ++j) {
                int k = j * 256 + l * 4;
                float4 kv = *(const float4*)&kp[k];
                float4 qv = *(const float4*)&qp[k];
                float4 w4 = *(const float4*)&wv[k];
                a += w4.x * tanh_f(qv.x + kv.x);
                a += w4.y * tanh_f(qv.y + kv.y);
                a += w4.z * tanh_f(qv.z + kv.z);
                a += w4.w * tanh_f(qv.w + kv.w);
            }
#pragma unroll
            for (int off = 32; off; off >>= 1) a += __shfl_xor(a, off, 64);
            if (l == 0) sc_ws[bb * 64 + ss] = a;
        }
        gbar(cnt, gen, 256);

        // ---- phase C: softmax + z = xW + attn*EOT + h@U + gates ----
        {
            float* hch = UNI;
            float* red = UNI;
            float xwv = bf2f(xW[(size_t)(b63 * 64 + t) * NG + n]);
            float acc[16];
#pragma unroll
            for (int i = 0; i < 16; ++i) acc[i] = 0.f;

            stage_h(hr, hch, 0, tid);
            if (tid < 64) {                    // per-b softmax (redundant per block)
                const int bb = tid;
                const int vl = valid_len[bb];
                float mx = -1e30f;
                for (int s2 = 0; s2 < 64; ++s2) {
                    float v = (s2 < vl) ? sc_ws[bb * 64 + s2] : -1000000.0f;
                    attn[bb * 68 + s2] = v;
                    mx = fmaxf(mx, v);
                }
                float sum = 0.f;
                for (int s2 = 0; s2 < 64; ++s2) {
                    float e = __expf(attn[bb * 68 + s2] - mx);
                    attn[bb * 68 + s2] = e;
                    sum += e;
                }
                float r = 1.f / sum;
                for (int s2 = 0; s2 < 64; ++s2) attn[bb * 68 + s2] *= r;
            }
            __syncthreads();

            float cx0 = 0.f, cx1 = 0.f, cx2 = 0.f, cx3 = 0.f;
            const float* ebase = EOT + ((size_t)b63 * 4096 + n) * 64;
            for (int c = 0; c < 4; ++c) {
#pragma unroll
                for (int j = 0; j < 4; ++j) {
                    float4 ev = *(const float4*)&ebase[c * 16 + j * 4];
                    float4 av = *(const float4*)&attn[b63 * 68 + c * 16 + j * 4];
                    cx0 += ev.x * av.x; cx1 += ev.y * av.y;
                    cx2 += ev.z * av.z; cx3 += ev.w * av.w;
                }
                hU_chunk(uchT, hch, c, nq, bq, w, acc);
                __syncthreads();
                if (c < 3) { stage_h(hr, hch, c + 1, tid); __syncthreads(); }
            }
#pragma unroll
            for (int jn = 0; jn < 4; ++jn)
#pragma unroll
                for (int jb = 0; jb < 4; ++jb)
                    red[((nq * 4 + jn) * 64 + jb * 16 + bq) * 17 + w] = acc[jn * 4 + jb];
            __syncthreads();
            float s = 0.f;
#pragma unroll
            for (int j = 0; j < 16; ++j) s += red[tid * 17 + j];
            zsm[nl * 65 + b63] = s + xwv + ((cx0 + cx1) + (cx2 + cx3));
            __syncthreads();
            if (tid < 256) gates_phase(t, blk, tid, zsm, creg, hw, hs_h, hs_l);
        }
        gbar(cnt, gen, 256);
    }
}

// ---------------------------------------------------------------------------
extern "C" void kernel_launch(void* const* d_in, const int* in_sizes, int n_in,
                              void* d_out, int out_size, void* d_ws, size_t ws_size,
                              hipStream_t stream)
{
    const int*   en        = (const int*)d_in[0];
    const int*   fr        = (const int*)d_in[1];
    const int*   valid_len = (const int*)d_in[2];
    const float* en_emb    = (const float*)d_in[3];
    const float* de_emb    = (const float*)d_in[4];
    const float* en_W      = (const float*)d_in[5];
    const float* en_U      = (const float*)d_in[6];
    const float* en_b      = (const float*)d_in[7];
    const float* de_W      = (const float*)d_in[8];
    const float* de_U      = (const float*)d_in[9];
    const float* de_b      = (const float*)d_in[10];
    const float* Wq        = (const float*)d_in[11];
    const float* Wk        = (const float*)d_in[12];
    const float* wv        = (const float*)d_in[13];
    const float* Wd        = (const float*)d_in[14];
    const float* bd        = (const float*)d_in[15];
    float* out = (float*)d_out;
    char*  ws  = (char*)d_ws;

    // ---- workspace regions (byte offsets; lifetimes annotated) ----
    float* ENUT  = (float*)(ws + 0);            // f32 [4096][1024] (.. encoder)
    float* EOT   = (float*)(ws + 0);            // f32 [64][4096][64] (EOT gemm .. decoder)
    short* WDT_H = (short*)(ws + 0);            // [16000][1024] (after decoder)
    short* WDT_L = (short*)(ws + 33554432);
    short* XWEN  = (short*)(ws + 67108864);     // bf16 [4096][4096] (.. encoder)
    float* KPROJ = (float*)(ws + 67108864);     // f32 [4096][1024] (after encoder)
    float* DEUT  = (float*)(ws + 83886080);     // f32 [4096][1024] (after encoder)
    short* XWFR  = (short*)(ws + 100663296);    // bf16 [4096][4096] (.. decoder)
    short* XEN   = (short*)(ws + 134217728);    // bf16 [4096][512] (.. xW gemms)
    short* XFR   = (short*)(ws + 138412032);
    float* HENC1 = (float*)(ws + 134217728);    // f32 [64][1024] enc h-pong (.. encoder)
    short* WCT_H = (short*)(ws + 134217728);    // bf16 [4096][1024] (after encoder .. EOT gemm)
    short* WCT_L = (short*)(ws + 142606336);
    short* HS_H  = (short*)(ws + 134217728);    // bf16 [4096][1024] (decoder ..)
    short* HS_L  = (short*)(ws + 142606336);
    short* ENWT  = (short*)(ws + 150994944);    // bf16 [4096][512]
    short* WXT   = (short*)(ws + 155189248);
    short* EO_H  = (short*)(ws + 150994944);    // bf16 [4096][1024] (encoder .. kproj gemm)
    short* EO_L  = (short*)(ws + 159383552);
    float* HDEC1 = (float*)(ws + 150994944);    // f32 [64][1024] dec h-pong (decoder ..)
    short* WKT_H = (short*)(ws + 167772160);    // bf16 [1024][1024]
    short* WKT_L = (short*)(ws + 169869312);
    float* HWS   = (float*)(ws + 173015040);    // [64][1024] h-ping
    float* CWS   = (float*)(ws + 173277184);    // [64][1024] c handoff
    float* QWS   = (float*)(ws + 173539328);    // [64][1024] q
    float* SCWS  = (float*)(ws + 173801472);    // [64][64]
    int*   BAR   = (int*)(ws + 173817856);      // cnt, gen

    zero16<<<1, 64, 0, stream>>>(BAR);

    // embedding gathers
    gather_bf16<<<4096, 256, 0, stream>>>(en_emb, en, XEN, EMBD);
    gather_bf16<<<4096, 256, 0, stream>>>(de_emb, fr, XFR, EMBD);
    // weight transposes needed before encoder
    transp_split<false><<<dim3(128, 16), 256, 0, stream>>>(en_W, NG, EMBD, ENWT, nullptr);
    transp_split<false><<<dim3(128, 16), 256, 0, stream>>>(de_W + (size_t)UNITS * NG, NG, EMBD, WXT, nullptr);
    transp_f32<<<dim3(128, 32), 256, 0, stream>>>(en_U, NG, UNITS, ENUT);

    // xW = X @ W + b   (bf16 out)
    gemm_split<2, false, false><<<dim3(32, 32), 256, 0, stream>>>(
        XEN, XEN, ENWT, ENWT, en_b, XWEN, NG, EMBD);
    gemm_split<2, false, false><<<dim3(32, 32), 256, 0, stream>>>(
        XFR, XFR, WXT, WXT, de_b, XWFR, NG, EMBD);

    // encoder (eo splits into ENWT region, dead; h-pong in XEN region, dead)
    encoder_persist<<<256, 1024, 0, stream>>>(
        XWEN, ENUT, HWS, HENC1, CWS, EO_H, EO_L, BAR, BAR + 8);

    // Wc^T split (into enc-h-pong region, dead after encoder)
    transp_split<true><<<dim3(128, 32), 256, 0, stream>>>(de_W, NG, UNITS, WCT_H, WCT_L);
    // de_U^T f32 (into XWEN upper half, dead after encoder)
    transp_f32<<<dim3(128, 32), 256, 0, stream>>>(de_U, NG, UNITS, DEUT);

    // EOT[b][n][s] = (en_o @ Wc) scattered   (f32, overwrites ENUT region)
    gemm_split<3, true, true><<<dim3(32, 32), 256, 0, stream>>>(
        EO_H, EO_L, WCT_H, WCT_L, nullptr, EOT, NG, UNITS);

    // Wk^T split, then kproj = en_o @ Wk (into XWEN lower half, dead)
    transp_split<true><<<dim3(32, 32), 256, 0, stream>>>(Wk, UNITS, UNITS, WKT_H, WKT_L);
    gemm_split<0, true, true><<<dim3(8, 32), 256, 0, stream>>>(
        EO_H, EO_L, WKT_H, WKT_L, nullptr, KPROJ, UNITS, UNITS);

    // decoder (hs splits into WCT region, dead; h-pong in EO region, dead)
    decoder_persist<<<256, 1024, 0, stream>>>(
        XWFR, DEUT, Wq, wv, KPROJ, EOT, valid_len,
        HWS, HDEC1, CWS, QWS, SCWS, HS_H, HS_L, BAR, BAR + 8);

    // Wd^T split (into EOT region, dead), then logits with [t][b]->[b][t] permute
    transp_split<true><<<dim3(500, 32), 256, 0, stream>>>(Wd, VFR, UNITS, WDT_H, WDT_L);
    gemm_split<1, true, true><<<dim3(125, 32), 256, 0, stream>>>(
        HS_H, HS_L, WDT_H, WDT_L, bd, out, VFR, UNITS);
}